// Round 2
// baseline (673.884 us; speedup 1.0000x reference)
//
#include <hip/hip_runtime.h>
#include <hip/hip_bf16.h>

#define NN 20000
#define NE 100000

typedef __attribute__((ext_vector_type(8))) short bf16x8;
typedef __attribute__((ext_vector_type(4))) float f32x4;
typedef __attribute__((ext_vector_type(16))) float f32x16;

// ---- ws layout ----
#define WS_RBFT 0u
#define WS_FLAG 131072u
#define WS_OFF  131328u                          // uint off[NN+1]
#define WS_CUR  (WS_OFF + 4u*(NN+1))             // uint cursor[NN]
#define WS_CNT  (WS_CUR + 4u*NN)                 // uint cnt[NN]
#define WS_INC  (WS_CNT + 4u*NN)                 // uint inc[2*NE]
#define WS_Y    (((WS_INC + 8u*NE) + 4095u) & ~4095u)
#define WS_NEED ((size_t)WS_Y + (size_t)NE * 2048u * 2u)

__device__ __forceinline__ unsigned short f2bf(float f) {
    unsigned u = __float_as_uint(f);
    u += 0x7fffu + ((u >> 16) & 1u);
    return (unsigned short)(u >> 16);
}
__device__ __forceinline__ float bf2f(unsigned s) {
    return __uint_as_float(s << 16);
}

// RbfT bf16 [pos(2048)][a(32)]; also zero the int64-detect flag
__global__ void prep_rbf_kernel(const float* __restrict__ R, unsigned short* __restrict__ RbfT,
                                int* __restrict__ flag) {
    int idx = blockIdx.x * blockDim.x + threadIdx.x;
    if (idx == 0) *flag = 0;
    if (idx >= 2048 * 32) return;
    int pos = idx >> 5;
    int a = idx & 31;
    RbfT[idx] = f2bf(R[a * 2048 + pos]);
}

__global__ void detect_kernel(const unsigned* __restrict__ w, int* __restrict__ flag) {
    int k = blockIdx.x * blockDim.x + threadIdx.x;
    if (k < NE && w[2 * k + 1] != 0) atomicOr(flag, 1);
}

__device__ __forceinline__ void decode_edge(const void* eidx, int use64, int e, int& src, int& dst) {
    if (use64) {
        const long long* p = (const long long*)eidx;
        src = (int)p[e]; dst = (int)p[NE + e];
    } else {
        const int* p = (const int*)eidx;
        src = p[e]; dst = p[NE + e];
    }
}

__global__ void count_kernel(const void* __restrict__ eidx, const int* __restrict__ flag,
                             unsigned* __restrict__ cnt) {
    int e = blockIdx.x * blockDim.x + threadIdx.x;
    if (e >= NE) return;
    int src, dst;
    decode_edge(eidx, *flag == 0, e, src, dst);
    if ((unsigned)src < NN) atomicAdd(&cnt[src], 1u);
    if ((unsigned)dst < NN) atomicAdd(&cnt[dst], 1u);
}

__global__ __launch_bounds__(1024) void scan_kernel(const unsigned* __restrict__ cnt,
                                                    unsigned* __restrict__ off,
                                                    unsigned* __restrict__ cur) {
    __shared__ unsigned sd[1024];
    const int t = threadIdx.x;
    unsigned vals[20];
    unsigned s = 0;
#pragma unroll
    for (int j = 0; j < 20; ++j) {
        int idx = t * 20 + j;
        unsigned v = (idx < NN) ? cnt[idx] : 0u;
        vals[j] = s; s += v;
    }
    sd[t] = s;
    __syncthreads();
    for (int d = 1; d < 1024; d <<= 1) {
        unsigned v = (t >= d) ? sd[t - d] : 0u;
        __syncthreads();
        sd[t] += v;
        __syncthreads();
    }
    unsigned base = (t > 0) ? sd[t - 1] : 0u;
#pragma unroll
    for (int j = 0; j < 20; ++j) {
        int idx = t * 20 + j;
        if (idx < NN) { unsigned o = base + vals[j]; off[idx] = o; cur[idx] = o; }
    }
    if (t == 1023) off[NN] = sd[1023];
}

__global__ void scatter_kernel(const void* __restrict__ eidx, const int* __restrict__ flag,
                               unsigned* __restrict__ cur, unsigned* __restrict__ inc) {
    int e = blockIdx.x * blockDim.x + threadIdx.x;
    if (e >= NE) return;
    int src, dst;
    decode_edge(eidx, *flag == 0, e, src, dst);
    if ((unsigned)src < NN) { unsigned p = atomicAdd(&cur[src], 1u); inc[p] = (unsigned)e; }
    if ((unsigned)dst < NN) { unsigned p = atomicAdd(&cur[dst], 1u); inc[p] = (unsigned)e | 0x80000000u; }
}

// ---- Pass 1: per edge, compute y_left/y_right and store bf16 to ws (no atomics) ----
__global__ __launch_bounds__(512, 3) void sheaf_pass1(
    const float* __restrict__ x,
    const void* __restrict__ eidx_raw,
    const float* __restrict__ ea,
    const unsigned short* __restrict__ RbfT,
    const int* __restrict__ flag,
    unsigned short* __restrict__ ybuf)
{
    __shared__ __align__(16) unsigned short F_lds[8 * 2048]; // [edge][side][32][32], rows XOR-swizzled
    __shared__ __align__(16) unsigned short dx_lds[8 * 1024]; // per-wave 32x32 bf16 staging

    const int tid  = threadIdx.x;
    const int lane = tid & 63;
    const int wv   = tid >> 6;
    const int e0   = blockIdx.x * 8;
    const int use64 = (*flag == 0);

    // ---- Phase 1: F[8 edges][2048] = ea @ R via mfma 16x16x32 (rows 8..15 duplicates, discarded)
    {
        const int arow = lane & 15;
        const int ab   = (lane >> 4) * 8;
        const float* eap = ea + (size_t)(e0 + (arow & 7)) * 32 + ab;
        f32x4 a0 = *(const f32x4*)eap;
        f32x4 a1 = *(const f32x4*)(eap + 4);
        bf16x8 afrag;
#pragma unroll
        for (int j = 0; j < 4; ++j) { afrag[j] = (short)f2bf(a0[j]); afrag[4 + j] = (short)f2bf(a1[j]); }

        const int pcol  = lane & 15;
        const int ebase = (lane >> 4) * 4;
#pragma unroll
        for (int t = 0; t < 16; ++t) {
            const int pos = wv * 256 + t * 16 + pcol;
            bf16x8 bfrag = *(const bf16x8*)(RbfT + pos * 32 + ab);
            f32x4 acc = {0.f, 0.f, 0.f, 0.f};
            acc = __builtin_amdgcn_mfma_f32_16x16x32_bf16(afrag, bfrag, acc, 0, 0, 0);
            const int side = pos >> 10;
            const int ij   = pos & 1023;      // i*32 + j
            const int i    = ij >> 5;
            const int soff = side * 1024 + (ij ^ ((i & 7) << 3));
#pragma unroll
            for (int r = 0; r < 4; ++r)
                if (ebase + r < 8) F_lds[(ebase + r) * 2048 + soff] = f2bf(acc[r]);
        }
    }
    __syncthreads();

    // ---- Phase 2: one wave per edge ----
    const int r31 = lane & 31;
    const int hi  = lane >> 5;
    const int kb  = hi * 8;
    unsigned short* dxb = dx_lds + wv * 1024;

    const int el = wv;
    const int e  = e0 + el;
    int src, dst;
    decode_edge(eidx_raw, use64, e, src, dst);
    if ((unsigned)src >= NN) src = 0;
    if ((unsigned)dst >= NN) dst = 0;

    const float* xl = x + (size_t)src * 1024 + r31;
    const float* xr = x + (size_t)dst * 1024 + r31;
    bf16x8 xlf0, xlf1, xrf0, xrf1;
#pragma unroll
    for (int j = 0; j < 8; ++j) {
        xlf0[j] = (short)f2bf(xl[(kb + j) * 32]);
        xlf1[j] = (short)f2bf(xl[(16 + kb + j) * 32]);
        xrf0[j] = (short)f2bf(-xr[(kb + j) * 32]);
        xrf1[j] = (short)f2bf(-xr[(16 + kb + j) * 32]);
    }

    const unsigned short* Fl = F_lds + el * 2048;
    const unsigned short* Fr = Fl + 1024;
    const int rbase = r31 * 32;
    const int rsw   = (r31 & 7) << 3;
    bf16x8 fl0 = *(const bf16x8*)(Fl + ((rbase + kb) ^ rsw));
    bf16x8 fl1 = *(const bf16x8*)(Fl + ((rbase + 16 + kb) ^ rsw));
    bf16x8 fr0 = *(const bf16x8*)(Fr + ((rbase + kb) ^ rsw));
    bf16x8 fr1 = *(const bf16x8*)(Fr + ((rbase + 16 + kb) ^ rsw));

    f32x16 dacc;
#pragma unroll
    for (int r = 0; r < 16; ++r) dacc[r] = 0.f;
    dacc = __builtin_amdgcn_mfma_f32_32x32x16_bf16(fl0, xlf0, dacc, 0, 0, 0);
    dacc = __builtin_amdgcn_mfma_f32_32x32x16_bf16(fl1, xlf1, dacc, 0, 0, 0);
    dacc = __builtin_amdgcn_mfma_f32_32x32x16_bf16(fr0, xrf0, dacc, 0, 0, 0);
    dacc = __builtin_amdgcn_mfma_f32_32x32x16_bf16(fr1, xrf1, dacc, 0, 0, 0);

    // dx -> LDS (bf16), read back as B-fragment
#pragma unroll
    for (int r = 0; r < 16; ++r) {
        const int row = (r & 3) + 8 * (r >> 2) + 4 * hi;
        dxb[row * 32 + r31] = f2bf(dacc[r]);
    }
    bf16x8 dxf0, dxf1;
#pragma unroll
    for (int j = 0; j < 8; ++j) {
        dxf0[j] = (short)dxb[(kb + j) * 32 + r31];
        dxf1[j] = (short)dxb[(16 + kb + j) * 32 + r31];
    }

    unsigned short* ydst = ybuf + (size_t)e * 2048;

    // y_left = F_l^T dx -> ybuf[e][0]
    {
        bf16x8 fT0, fT1;
#pragma unroll
        for (int j = 0; j < 8; ++j) {
            const int k0 = kb + j, k1 = 16 + kb + j;
            fT0[j] = (short)Fl[(k0 * 32 + r31) ^ ((k0 & 7) << 3)];
            fT1[j] = (short)Fl[(k1 * 32 + r31) ^ ((k1 & 7) << 3)];
        }
        f32x16 y;
#pragma unroll
        for (int r = 0; r < 16; ++r) y[r] = 0.f;
        y = __builtin_amdgcn_mfma_f32_32x32x16_bf16(fT0, dxf0, y, 0, 0, 0);
        y = __builtin_amdgcn_mfma_f32_32x32x16_bf16(fT1, dxf1, y, 0, 0, 0);
#pragma unroll
        for (int r = 0; r < 16; ++r) {
            const int row = (r & 3) + 8 * (r >> 2) + 4 * hi;
            dxb[row * 32 + r31] = f2bf(y[r]);
        }
        bf16x8 s0 = *(const bf16x8*)(dxb + lane * 8);
        bf16x8 s1 = *(const bf16x8*)(dxb + 512 + lane * 8);
        *(bf16x8*)(ydst + lane * 8) = s0;
        *(bf16x8*)(ydst + 512 + lane * 8) = s1;
    }

    // y_right = F_r^T dx -> ybuf[e][1]
    {
        bf16x8 fT0, fT1;
#pragma unroll
        for (int j = 0; j < 8; ++j) {
            const int k0 = kb + j, k1 = 16 + kb + j;
            fT0[j] = (short)Fr[(k0 * 32 + r31) ^ ((k0 & 7) << 3)];
            fT1[j] = (short)Fr[(k1 * 32 + r31) ^ ((k1 & 7) << 3)];
        }
        f32x16 y;
#pragma unroll
        for (int r = 0; r < 16; ++r) y[r] = 0.f;
        y = __builtin_amdgcn_mfma_f32_32x32x16_bf16(fT0, dxf0, y, 0, 0, 0);
        y = __builtin_amdgcn_mfma_f32_32x32x16_bf16(fT1, dxf1, y, 0, 0, 0);
#pragma unroll
        for (int r = 0; r < 16; ++r) {
            const int row = (r & 3) + 8 * (r >> 2) + 4 * hi;
            dxb[row * 32 + r31] = f2bf(y[r]);
        }
        bf16x8 s0 = *(const bf16x8*)(dxb + lane * 8);
        bf16x8 s1 = *(const bf16x8*)(dxb + 512 + lane * 8);
        *(bf16x8*)(ydst + 1024 + lane * 8) = s0;
        *(bf16x8*)(ydst + 1536 + lane * 8) = s1;
    }
}

// ---- Pass 2: per node, gather-sum incident y rows; writes every output row once ----
__global__ __launch_bounds__(256, 8) void sheaf_pass2(
    const unsigned* __restrict__ off, const unsigned* __restrict__ inc,
    const unsigned short* __restrict__ ybuf, float* __restrict__ out)
{
    const int n = blockIdx.x;
    const int t = threadIdx.x;
    unsigned i = off[n], end = off[n + 1];
    float a0 = 0.f, a1 = 0.f, a2 = 0.f, a3 = 0.f;

    while (i + 2 <= end) {
        unsigned v1 = inc[i], v2 = inc[i + 1];
        float g1 = (v1 >> 31) ? -1.f : 1.f;
        float g2 = (v2 >> 31) ? -1.f : 1.f;
        const unsigned* p1 = (const unsigned*)(ybuf + ((size_t)(v1 & 0x7fffffffu) * 2 + (v1 >> 31)) * 1024) + 2 * t;
        const unsigned* p2 = (const unsigned*)(ybuf + ((size_t)(v2 & 0x7fffffffu) * 2 + (v2 >> 31)) * 1024) + 2 * t;
        unsigned w0 = p1[0], w1 = p1[1];
        unsigned u0 = p2[0], u1 = p2[1];
        a0 += g1 * bf2f(w0 & 0xffffu); a1 += g1 * bf2f(w0 >> 16);
        a2 += g1 * bf2f(w1 & 0xffffu); a3 += g1 * bf2f(w1 >> 16);
        a0 += g2 * bf2f(u0 & 0xffffu); a1 += g2 * bf2f(u0 >> 16);
        a2 += g2 * bf2f(u1 & 0xffffu); a3 += g2 * bf2f(u1 >> 16);
        i += 2;
    }
    if (i < end) {
        unsigned v1 = inc[i];
        float g1 = (v1 >> 31) ? -1.f : 1.f;
        const unsigned* p1 = (const unsigned*)(ybuf + ((size_t)(v1 & 0x7fffffffu) * 2 + (v1 >> 31)) * 1024) + 2 * t;
        unsigned w0 = p1[0], w1 = p1[1];
        a0 += g1 * bf2f(w0 & 0xffffu); a1 += g1 * bf2f(w0 >> 16);
        a2 += g1 * bf2f(w1 & 0xffffu); a3 += g1 * bf2f(w1 >> 16);
    }
    f32x4 o = {a0, a1, a2, a3};
    *(f32x4*)(out + (size_t)n * 1024 + 4 * t) = o;
}

// ---- Fallback: previous working atomic kernel (used only if ws too small) ----
__global__ __launch_bounds__(512, 4) void sheaf_atomic(
    const float* __restrict__ x,
    const void* __restrict__ eidx_raw,
    const float* __restrict__ ea,
    const unsigned short* __restrict__ RbfT,
    const int* __restrict__ flag,
    float* __restrict__ out)
{
    __shared__ __align__(16) unsigned short F_lds[16 * 2048];
    __shared__ __align__(16) unsigned short dx_lds[8 * 1024];

    const int tid  = threadIdx.x;
    const int lane = tid & 63;
    const int wv   = tid >> 6;
    const int e0   = blockIdx.x * 16;
    const int use64 = (*flag == 0);

    {
        const int arow = lane & 15;
        const int ab   = (lane >> 4) * 8;
        const float* eap = ea + (size_t)(e0 + arow) * 32 + ab;
        f32x4 a0 = *(const f32x4*)eap;
        f32x4 a1 = *(const f32x4*)(eap + 4);
        bf16x8 afrag;
#pragma unroll
        for (int j = 0; j < 4; ++j) { afrag[j] = (short)f2bf(a0[j]); afrag[4 + j] = (short)f2bf(a1[j]); }
        const int pcol  = lane & 15;
        const int ebase = (lane >> 4) * 4;
#pragma unroll
        for (int t = 0; t < 16; ++t) {
            const int pos = wv * 256 + t * 16 + pcol;
            bf16x8 bfrag = *(const bf16x8*)(RbfT + pos * 32 + ab);
            f32x4 acc = {0.f, 0.f, 0.f, 0.f};
            acc = __builtin_amdgcn_mfma_f32_16x16x32_bf16(afrag, bfrag, acc, 0, 0, 0);
            const int side = pos >> 10;
            const int ij   = pos & 1023;
            const int i    = ij >> 5;
            const int soff = side * 1024 + (ij ^ ((i & 7) << 3));
#pragma unroll
            for (int r = 0; r < 4; ++r)
                F_lds[(ebase + r) * 2048 + soff] = f2bf(acc[r]);
        }
    }
    __syncthreads();

    const int r31 = lane & 31;
    const int hi  = lane >> 5;
    const int kb  = hi * 8;
    unsigned short* dxb = dx_lds + wv * 1024;

#pragma unroll 1
    for (int sub = 0; sub < 2; ++sub) {
        const int el = wv * 2 + sub;
        const int e  = e0 + el;
        int src, dst;
        decode_edge(eidx_raw, use64, e, src, dst);
        if ((unsigned)src >= NN || (unsigned)dst >= NN) continue;

        const float* xl = x + (size_t)src * 1024 + r31;
        const float* xr = x + (size_t)dst * 1024 + r31;
        bf16x8 xlf0, xlf1, xrf0, xrf1;
#pragma unroll
        for (int j = 0; j < 8; ++j) {
            xlf0[j] = (short)f2bf(xl[(kb + j) * 32]);
            xlf1[j] = (short)f2bf(xl[(16 + kb + j) * 32]);
            xrf0[j] = (short)f2bf(-xr[(kb + j) * 32]);
            xrf1[j] = (short)f2bf(-xr[(16 + kb + j) * 32]);
        }
        const unsigned short* Fl = F_lds + el * 2048;
        const unsigned short* Fr = Fl + 1024;
        const int rbase = r31 * 32;
        const int rsw   = (r31 & 7) << 3;
        bf16x8 fl0 = *(const bf16x8*)(Fl + ((rbase + kb) ^ rsw));
        bf16x8 fl1 = *(const bf16x8*)(Fl + ((rbase + 16 + kb) ^ rsw));
        bf16x8 fr0 = *(const bf16x8*)(Fr + ((rbase + kb) ^ rsw));
        bf16x8 fr1 = *(const bf16x8*)(Fr + ((rbase + 16 + kb) ^ rsw));

        f32x16 dacc;
#pragma unroll
        for (int r = 0; r < 16; ++r) dacc[r] = 0.f;
        dacc = __builtin_amdgcn_mfma_f32_32x32x16_bf16(fl0, xlf0, dacc, 0, 0, 0);
        dacc = __builtin_amdgcn_mfma_f32_32x32x16_bf16(fl1, xlf1, dacc, 0, 0, 0);
        dacc = __builtin_amdgcn_mfma_f32_32x32x16_bf16(fr0, xrf0, dacc, 0, 0, 0);
        dacc = __builtin_amdgcn_mfma_f32_32x32x16_bf16(fr1, xrf1, dacc, 0, 0, 0);

#pragma unroll
        for (int r = 0; r < 16; ++r) {
            const int row = (r & 3) + 8 * (r >> 2) + 4 * hi;
            dxb[row * 32 + r31] = f2bf(dacc[r]);
        }
        bf16x8 dxf0, dxf1;
#pragma unroll
        for (int j = 0; j < 8; ++j) {
            dxf0[j] = (short)dxb[(kb + j) * 32 + r31];
            dxf1[j] = (short)dxb[(16 + kb + j) * 32 + r31];
        }

        bf16x8 flT0, flT1;
#pragma unroll
        for (int j = 0; j < 8; ++j) {
            const int k0 = kb + j, k1 = 16 + kb + j;
            flT0[j] = (short)Fl[(k0 * 32 + r31) ^ ((k0 & 7) << 3)];
            flT1[j] = (short)Fl[(k1 * 32 + r31) ^ ((k1 & 7) << 3)];
        }
        f32x16 yl;
#pragma unroll
        for (int r = 0; r < 16; ++r) yl[r] = 0.f;
        yl = __builtin_amdgcn_mfma_f32_32x32x16_bf16(flT0, dxf0, yl, 0, 0, 0);
        yl = __builtin_amdgcn_mfma_f32_32x32x16_bf16(flT1, dxf1, yl, 0, 0, 0);
        float* outs = out + (size_t)src * 1024 + r31;
#pragma unroll
        for (int r = 0; r < 16; ++r) {
            const int row = (r & 3) + 8 * (r >> 2) + 4 * hi;
            atomicAdd(outs + row * 32, yl[r]);
        }

        bf16x8 frT0, frT1;
#pragma unroll
        for (int j = 0; j < 8; ++j) {
            const int k0 = kb + j, k1 = 16 + kb + j;
            frT0[j] = (short)Fr[(k0 * 32 + r31) ^ ((k0 & 7) << 3)];
            frT1[j] = (short)Fr[(k1 * 32 + r31) ^ ((k1 & 7) << 3)];
        }
        f32x16 yr;
#pragma unroll
        for (int r = 0; r < 16; ++r) yr[r] = 0.f;
        yr = __builtin_amdgcn_mfma_f32_32x32x16_bf16(frT0, dxf0, yr, 0, 0, 0);
        yr = __builtin_amdgcn_mfma_f32_32x32x16_bf16(frT1, dxf1, yr, 0, 0, 0);
        float* outd = out + (size_t)dst * 1024 + r31;
#pragma unroll
        for (int r = 0; r < 16; ++r) {
            const int row = (r & 3) + 8 * (r >> 2) + 4 * hi;
            atomicAdd(outd + row * 32, -yr[r]);
        }
    }
}

extern "C" void kernel_launch(void* const* d_in, const int* in_sizes, int n_in,
                              void* d_out, int out_size, void* d_ws, size_t ws_size,
                              hipStream_t stream) {
    const float* x  = (const float*)d_in[0];
    const void* eidx = d_in[1];
    const float* ea = (const float*)d_in[2];
    const float* R  = (const float*)d_in[3];
    float* out = (float*)d_out;
    char* ws = (char*)d_ws;

    unsigned short* RbfT = (unsigned short*)(ws + WS_RBFT);
    int* flag = (int*)(ws + WS_FLAG);

    prep_rbf_kernel<<<256, 256, 0, stream>>>(R, RbfT, flag);
    detect_kernel<<<(NE + 255) / 256, 256, 0, stream>>>((const unsigned*)eidx, flag);

    if (ws_size >= WS_NEED) {
        unsigned* off = (unsigned*)(ws + WS_OFF);
        unsigned* cur = (unsigned*)(ws + WS_CUR);
        unsigned* cnt = (unsigned*)(ws + WS_CNT);
        unsigned* inc = (unsigned*)(ws + WS_INC);
        unsigned short* ybuf = (unsigned short*)(ws + WS_Y);

        hipMemsetAsync(cnt, 0, 4u * NN, stream);
        count_kernel<<<(NE + 255) / 256, 256, 0, stream>>>(eidx, flag, cnt);
        scan_kernel<<<1, 1024, 0, stream>>>(cnt, off, cur);
        scatter_kernel<<<(NE + 255) / 256, 256, 0, stream>>>(eidx, flag, cur, inc);
        sheaf_pass1<<<NE / 8, 512, 0, stream>>>(x, eidx, ea, RbfT, flag, ybuf);
        sheaf_pass2<<<NN, 256, 0, stream>>>(off, inc, ybuf, out);
    } else {
        hipMemsetAsync(d_out, 0, (size_t)out_size * sizeof(float), stream);
        sheaf_atomic<<<NE / 16, 512, 0, stream>>>(x, eidx, ea, RbfT, flag, out);
    }
}

// Round 3
// 448.546 us; speedup vs baseline: 1.5024x; 1.5024x over previous
//
#include <hip/hip_runtime.h>
#include <hip/hip_bf16.h>

#define NN 20000
#define NE 100000
#define SLOTS 16

typedef __attribute__((ext_vector_type(8))) short bf16x8;
typedef __attribute__((ext_vector_type(4))) float f32x4;
typedef __attribute__((ext_vector_type(16))) float f32x16;

// ---- ws layout (CSR path needs ~1.17 MB) ----
#define WS_RBFT 0u
#define WS_FLAG 131072u
#define WS_OFF  131328u                          // uint off[NN+1]
#define WS_CUR  (WS_OFF + 4u*(NN+1))             // uint cur[NN]
#define WS_CNT  (WS_CUR + 4u*NN)                 // uint cnt[NN]
#define WS_INC  (WS_CNT + 4u*NN)                 // uint inc[2*NE]
#define WS_NEED ((size_t)WS_INC + 8u*NE)

__device__ __forceinline__ unsigned short f2bf(float f) {
    unsigned u = __float_as_uint(f);
    u += 0x7fffu + ((u >> 16) & 1u);
    return (unsigned short)(u >> 16);
}

// RbfT bf16 [pos(2048)][a(32)]; also zero the int64-detect flag
__global__ void prep_rbf_kernel(const float* __restrict__ R, unsigned short* __restrict__ RbfT,
                                int* __restrict__ flag) {
    int idx = blockIdx.x * blockDim.x + threadIdx.x;
    if (idx == 0) *flag = 0;
    if (idx >= 2048 * 32) return;
    int pos = idx >> 5;
    int a = idx & 31;
    RbfT[idx] = f2bf(R[a * 2048 + pos]);
}

__global__ void detect_kernel(const unsigned* __restrict__ w, int* __restrict__ flag) {
    int k = blockIdx.x * blockDim.x + threadIdx.x;
    if (k < NE && w[2 * k + 1] != 0) atomicOr(flag, 1);
}

__device__ __forceinline__ void decode_edge(const void* eidx, int use64, int e, int& src, int& dst) {
    if (use64) {
        const long long* p = (const long long*)eidx;
        src = (int)p[e]; dst = (int)p[NE + e];
    } else {
        const int* p = (const int*)eidx;
        src = p[e]; dst = p[NE + e];
    }
}

__global__ void count_kernel(const void* __restrict__ eidx, const int* __restrict__ flag,
                             unsigned* __restrict__ cnt) {
    int e = blockIdx.x * blockDim.x + threadIdx.x;
    if (e >= NE) return;
    int src, dst;
    decode_edge(eidx, *flag == 0, e, src, dst);
    if ((unsigned)src < NN) atomicAdd(&cnt[src], 1u);
    if ((unsigned)dst < NN) atomicAdd(&cnt[dst], 1u);
}

__global__ __launch_bounds__(1024) void scan_kernel(const unsigned* __restrict__ cnt,
                                                    unsigned* __restrict__ off,
                                                    unsigned* __restrict__ cur) {
    __shared__ unsigned sd[1024];
    const int t = threadIdx.x;
    unsigned vals[20];
    unsigned s = 0;
#pragma unroll
    for (int j = 0; j < 20; ++j) {
        int idx = t * 20 + j;
        unsigned v = (idx < NN) ? cnt[idx] : 0u;
        vals[j] = s; s += v;
    }
    sd[t] = s;
    __syncthreads();
    for (int d = 1; d < 1024; d <<= 1) {
        unsigned v = (t >= d) ? sd[t - d] : 0u;
        __syncthreads();
        sd[t] += v;
        __syncthreads();
    }
    unsigned base = (t > 0) ? sd[t - 1] : 0u;
#pragma unroll
    for (int j = 0; j < 20; ++j) {
        int idx = t * 20 + j;
        if (idx < NN) { unsigned o = base + vals[j]; off[idx] = o; cur[idx] = o; }
    }
    if (t == 1023) off[NN] = sd[1023];
}

__global__ void scatter_kernel(const void* __restrict__ eidx, const int* __restrict__ flag,
                               unsigned* __restrict__ cur, unsigned* __restrict__ inc) {
    int e = blockIdx.x * blockDim.x + threadIdx.x;
    if (e >= NE) return;
    int src, dst;
    decode_edge(eidx, *flag == 0, e, src, dst);
    if ((unsigned)src < NN) { unsigned p = atomicAdd(&cur[src], 1u); inc[p] = (unsigned)e; }
    if ((unsigned)dst < NN) { unsigned p = atomicAdd(&cur[dst], 1u); inc[p] = (unsigned)e | 0x80000000u; }
}

// ---- Node-centric kernel: one block per node, zero atomics ----
__global__ __launch_bounds__(256, 2) void sheaf_node(
    const float* __restrict__ x,
    const void* __restrict__ eidx_raw,
    const float* __restrict__ ea,
    const unsigned short* __restrict__ RbfT,
    const int* __restrict__ flag,
    const unsigned* __restrict__ off,
    const unsigned* __restrict__ inc,
    float* __restrict__ out)
{
    __shared__ __align__(16) unsigned short F_lds[SLOTS * 2048]; // 64KB; [slot][side][32][32] rows XOR-swizzled
    __shared__ __align__(16) unsigned short dx_lds[4 * 1024];    // per-wave 32x32 bf16 staging
    __shared__ int slot_src[SLOTS], slot_dst[SLOTS], slot_side[SLOTS], slot_e[SLOTS];

    const int n    = blockIdx.x;
    const int tid  = threadIdx.x;
    const int lane = tid & 63;
    const int wv   = tid >> 6;
    const int use64 = (*flag == 0);

    const unsigned start = off[n], end = off[n + 1];
    const int deg = (int)(end - start);

    const int r31 = lane & 31;
    const int hi  = lane >> 5;
    const int kb  = hi * 8;
    unsigned short* dxb = dx_lds + wv * 1024;

    f32x16 acc;
#pragma unroll
    for (int r = 0; r < 16; ++r) acc[r] = 0.f;

    for (int base = 0; base < deg; base += SLOTS) {
        __syncthreads();   // previous batch fully consumed before overwriting F_lds
        if (tid < SLOTS) {
            int p = base + tid;
            if (p < deg) {
                unsigned v = inc[start + p];
                int e = (int)(v & 0x7fffffffu);
                int s, d; decode_edge(eidx_raw, use64, e, s, d);
                if ((unsigned)s >= NN) s = 0;
                if ((unsigned)d >= NN) d = 0;
                slot_e[tid] = e; slot_src[tid] = s; slot_dst[tid] = d;
                slot_side[tid] = (int)(v >> 31);
            } else slot_e[tid] = -1;
        }
        __syncthreads();

        // ---- Phase A: F for up to 16 slots (ea @ R via mfma 16x16x32) ----
        {
            const int arow = lane & 15;
            const int ab   = (lane >> 4) * 8;
            const int e    = slot_e[arow];
            bf16x8 afrag = {0, 0, 0, 0, 0, 0, 0, 0};
            if (e >= 0) {
                const float* eap = ea + (size_t)e * 32 + ab;
                f32x4 a0 = *(const f32x4*)eap;
                f32x4 a1 = *(const f32x4*)(eap + 4);
#pragma unroll
                for (int j = 0; j < 4; ++j) { afrag[j] = (short)f2bf(a0[j]); afrag[4 + j] = (short)f2bf(a1[j]); }
            }
            const int pcol  = lane & 15;
            const int ebase = (lane >> 4) * 4;
#pragma unroll 8
            for (int t = 0; t < 32; ++t) {
                const int pos = wv * 512 + t * 16 + pcol;
                bf16x8 bfrag = *(const bf16x8*)(RbfT + pos * 32 + ab);
                f32x4 c = {0.f, 0.f, 0.f, 0.f};
                c = __builtin_amdgcn_mfma_f32_16x16x32_bf16(afrag, bfrag, c, 0, 0, 0);
                const int side = pos >> 10;
                const int ij   = pos & 1023;      // i*32 + j
                const int i    = ij >> 5;
                const int soff = side * 1024 + (ij ^ ((i & 7) << 3));
#pragma unroll
                for (int r = 0; r < 4; ++r)
                    F_lds[(ebase + r) * 2048 + soff] = f2bf(c[r]);
            }
        }
        __syncthreads();

        // ---- Phase B: wave wv handles slots wv, wv+4, wv+8, wv+12 ----
#pragma unroll 1
        for (int si = wv; si < SLOTS; si += 4) {
            if (base + si >= deg) break;
            const int src  = slot_src[si];
            const int dst  = slot_dst[si];
            const int side = slot_side[si];

            const float* xl = x + (size_t)src * 1024 + r31;
            const float* xr = x + (size_t)dst * 1024 + r31;
            bf16x8 xlf0, xlf1, xrf0, xrf1;
#pragma unroll
            for (int j = 0; j < 8; ++j) {
                xlf0[j] = (short)f2bf(xl[(kb + j) * 32]);
                xlf1[j] = (short)f2bf(xl[(16 + kb + j) * 32]);
                xrf0[j] = (short)f2bf(-xr[(kb + j) * 32]);
                xrf1[j] = (short)f2bf(-xr[(16 + kb + j) * 32]);
            }

            const unsigned short* Fl = F_lds + si * 2048;
            const unsigned short* Fr = Fl + 1024;
            const int rbase = r31 * 32;
            const int rsw   = (r31 & 7) << 3;
            bf16x8 fl0 = *(const bf16x8*)(Fl + ((rbase + kb) ^ rsw));
            bf16x8 fl1 = *(const bf16x8*)(Fl + ((rbase + 16 + kb) ^ rsw));
            bf16x8 fr0 = *(const bf16x8*)(Fr + ((rbase + kb) ^ rsw));
            bf16x8 fr1 = *(const bf16x8*)(Fr + ((rbase + 16 + kb) ^ rsw));

            f32x16 dacc;
#pragma unroll
            for (int r = 0; r < 16; ++r) dacc[r] = 0.f;
            dacc = __builtin_amdgcn_mfma_f32_32x32x16_bf16(fl0, xlf0, dacc, 0, 0, 0);
            dacc = __builtin_amdgcn_mfma_f32_32x32x16_bf16(fl1, xlf1, dacc, 0, 0, 0);
            dacc = __builtin_amdgcn_mfma_f32_32x32x16_bf16(fr0, xrf0, dacc, 0, 0, 0);
            dacc = __builtin_amdgcn_mfma_f32_32x32x16_bf16(fr1, xrf1, dacc, 0, 0, 0);

            // dx -> LDS (bf16, sign folded), read back as B-fragment (same-wave DS order)
            const float sgn = side ? -1.f : 1.f;
#pragma unroll
            for (int r = 0; r < 16; ++r) {
                const int row = (r & 3) + 8 * (r >> 2) + 4 * hi;
                dxb[row * 32 + r31] = f2bf(sgn * dacc[r]);
            }
            bf16x8 dxf0, dxf1;
#pragma unroll
            for (int j = 0; j < 8; ++j) {
                dxf0[j] = (short)dxb[(kb + j) * 32 + r31];
                dxf1[j] = (short)dxb[(16 + kb + j) * 32 + r31];
            }

            // acc += F_side^T (sgn*dx)
            const unsigned short* Fs = side ? Fr : Fl;
            bf16x8 fT0, fT1;
#pragma unroll
            for (int j = 0; j < 8; ++j) {
                const int k0 = kb + j, k1 = 16 + kb + j;
                fT0[j] = (short)Fs[(k0 * 32 + r31) ^ ((k0 & 7) << 3)];
                fT1[j] = (short)Fs[(k1 * 32 + r31) ^ ((k1 & 7) << 3)];
            }
            acc = __builtin_amdgcn_mfma_f32_32x32x16_bf16(fT0, dxf0, acc, 0, 0, 0);
            acc = __builtin_amdgcn_mfma_f32_32x32x16_bf16(fT1, dxf1, acc, 0, 0, 0);
        }
    }

    // ---- cross-wave reduce (reuse F_lds as f32 [4][32][32]) ----
    __syncthreads();
    float* red = (float*)F_lds;
#pragma unroll
    for (int r = 0; r < 16; ++r) {
        const int row = (r & 3) + 8 * (r >> 2) + 4 * hi;
        red[wv * 1024 + row * 32 + r31] = acc[r];
    }
    __syncthreads();
    {
        const int p4 = tid * 4;
        f32x4 s0 = *(const f32x4*)(red + p4);
        f32x4 s1 = *(const f32x4*)(red + 1024 + p4);
        f32x4 s2 = *(const f32x4*)(red + 2048 + p4);
        f32x4 s3 = *(const f32x4*)(red + 3072 + p4);
        f32x4 o;
#pragma unroll
        for (int j = 0; j < 4; ++j) o[j] = (s0[j] + s1[j]) + (s2[j] + s3[j]);
        *(f32x4*)(out + (size_t)n * 1024 + p4) = o;
    }
}

// ---- Fallback: proven atomic kernel (used only if ws absurdly small) ----
__global__ __launch_bounds__(512, 4) void sheaf_atomic(
    const float* __restrict__ x,
    const void* __restrict__ eidx_raw,
    const float* __restrict__ ea,
    const unsigned short* __restrict__ RbfT,
    const int* __restrict__ flag,
    float* __restrict__ out)
{
    __shared__ __align__(16) unsigned short F_lds[16 * 2048];
    __shared__ __align__(16) unsigned short dx_lds[8 * 1024];

    const int tid  = threadIdx.x;
    const int lane = tid & 63;
    const int wv   = tid >> 6;
    const int e0   = blockIdx.x * 16;
    const int use64 = (*flag == 0);

    {
        const int arow = lane & 15;
        const int ab   = (lane >> 4) * 8;
        const float* eap = ea + (size_t)(e0 + arow) * 32 + ab;
        f32x4 a0 = *(const f32x4*)eap;
        f32x4 a1 = *(const f32x4*)(eap + 4);
        bf16x8 afrag;
#pragma unroll
        for (int j = 0; j < 4; ++j) { afrag[j] = (short)f2bf(a0[j]); afrag[4 + j] = (short)f2bf(a1[j]); }
        const int pcol  = lane & 15;
        const int ebase = (lane >> 4) * 4;
#pragma unroll
        for (int t = 0; t < 16; ++t) {
            const int pos = wv * 256 + t * 16 + pcol;
            bf16x8 bfrag = *(const bf16x8*)(RbfT + pos * 32 + ab);
            f32x4 c = {0.f, 0.f, 0.f, 0.f};
            c = __builtin_amdgcn_mfma_f32_16x16x32_bf16(afrag, bfrag, c, 0, 0, 0);
            const int side = pos >> 10;
            const int ij   = pos & 1023;
            const int i    = ij >> 5;
            const int soff = side * 1024 + (ij ^ ((i & 7) << 3));
#pragma unroll
            for (int r = 0; r < 4; ++r)
                F_lds[(ebase + r) * 2048 + soff] = f2bf(c[r]);
        }
    }
    __syncthreads();

    const int r31 = lane & 31;
    const int hi  = lane >> 5;
    const int kb  = hi * 8;
    unsigned short* dxb = dx_lds + wv * 1024;

#pragma unroll 1
    for (int sub = 0; sub < 2; ++sub) {
        const int el = wv * 2 + sub;
        const int e  = e0 + el;
        int src, dst;
        decode_edge(eidx_raw, use64, e, src, dst);
        if ((unsigned)src >= NN || (unsigned)dst >= NN) continue;

        const float* xl = x + (size_t)src * 1024 + r31;
        const float* xr = x + (size_t)dst * 1024 + r31;
        bf16x8 xlf0, xlf1, xrf0, xrf1;
#pragma unroll
        for (int j = 0; j < 8; ++j) {
            xlf0[j] = (short)f2bf(xl[(kb + j) * 32]);
            xlf1[j] = (short)f2bf(xl[(16 + kb + j) * 32]);
            xrf0[j] = (short)f2bf(-xr[(kb + j) * 32]);
            xrf1[j] = (short)f2bf(-xr[(16 + kb + j) * 32]);
        }
        const unsigned short* Fl = F_lds + el * 2048;
        const unsigned short* Fr = Fl + 1024;
        const int rbase = r31 * 32;
        const int rsw   = (r31 & 7) << 3;
        bf16x8 fl0 = *(const bf16x8*)(Fl + ((rbase + kb) ^ rsw));
        bf16x8 fl1 = *(const bf16x8*)(Fl + ((rbase + 16 + kb) ^ rsw));
        bf16x8 fr0 = *(const bf16x8*)(Fr + ((rbase + kb) ^ rsw));
        bf16x8 fr1 = *(const bf16x8*)(Fr + ((rbase + 16 + kb) ^ rsw));

        f32x16 dacc;
#pragma unroll
        for (int r = 0; r < 16; ++r) dacc[r] = 0.f;
        dacc = __builtin_amdgcn_mfma_f32_32x32x16_bf16(fl0, xlf0, dacc, 0, 0, 0);
        dacc = __builtin_amdgcn_mfma_f32_32x32x16_bf16(fl1, xlf1, dacc, 0, 0, 0);
        dacc = __builtin_amdgcn_mfma_f32_32x32x16_bf16(fr0, xrf0, dacc, 0, 0, 0);
        dacc = __builtin_amdgcn_mfma_f32_32x32x16_bf16(fr1, xrf1, dacc, 0, 0, 0);

#pragma unroll
        for (int r = 0; r < 16; ++r) {
            const int row = (r & 3) + 8 * (r >> 2) + 4 * hi;
            dxb[row * 32 + r31] = f2bf(dacc[r]);
        }
        bf16x8 dxf0, dxf1;
#pragma unroll
        for (int j = 0; j < 8; ++j) {
            dxf0[j] = (short)dxb[(kb + j) * 32 + r31];
            dxf1[j] = (short)dxb[(16 + kb + j) * 32 + r31];
        }

        bf16x8 flT0, flT1;
#pragma unroll
        for (int j = 0; j < 8; ++j) {
            const int k0 = kb + j, k1 = 16 + kb + j;
            flT0[j] = (short)Fl[(k0 * 32 + r31) ^ ((k0 & 7) << 3)];
            flT1[j] = (short)Fl[(k1 * 32 + r31) ^ ((k1 & 7) << 3)];
        }
        f32x16 yl;
#pragma unroll
        for (int r = 0; r < 16; ++r) yl[r] = 0.f;
        yl = __builtin_amdgcn_mfma_f32_32x32x16_bf16(flT0, dxf0, yl, 0, 0, 0);
        yl = __builtin_amdgcn_mfma_f32_32x32x16_bf16(flT1, dxf1, yl, 0, 0, 0);
        float* outs = out + (size_t)src * 1024 + r31;
#pragma unroll
        for (int r = 0; r < 16; ++r) {
            const int row = (r & 3) + 8 * (r >> 2) + 4 * hi;
            atomicAdd(outs + row * 32, yl[r]);
        }

        bf16x8 frT0, frT1;
#pragma unroll
        for (int j = 0; j < 8; ++j) {
            const int k0 = kb + j, k1 = 16 + kb + j;
            frT0[j] = (short)Fr[(k0 * 32 + r31) ^ ((k0 & 7) << 3)];
            frT1[j] = (short)Fr[(k1 * 32 + r31) ^ ((k1 & 7) << 3)];
        }
        f32x16 yr;
#pragma unroll
        for (int r = 0; r < 16; ++r) yr[r] = 0.f;
        yr = __builtin_amdgcn_mfma_f32_32x32x16_bf16(frT0, dxf0, yr, 0, 0, 0);
        yr = __builtin_amdgcn_mfma_f32_32x32x16_bf16(frT1, dxf1, yr, 0, 0, 0);
        float* outd = out + (size_t)dst * 1024 + r31;
#pragma unroll
        for (int r = 0; r < 16; ++r) {
            const int row = (r & 3) + 8 * (r >> 2) + 4 * hi;
            atomicAdd(outd + row * 32, -yr[r]);
        }
    }
}

extern "C" void kernel_launch(void* const* d_in, const int* in_sizes, int n_in,
                              void* d_out, int out_size, void* d_ws, size_t ws_size,
                              hipStream_t stream) {
    const float* x  = (const float*)d_in[0];
    const void* eidx = d_in[1];
    const float* ea = (const float*)d_in[2];
    const float* R  = (const float*)d_in[3];
    float* out = (float*)d_out;
    char* ws = (char*)d_ws;

    unsigned short* RbfT = (unsigned short*)(ws + WS_RBFT);
    int* flag = (int*)(ws + WS_FLAG);

    prep_rbf_kernel<<<256, 256, 0, stream>>>(R, RbfT, flag);
    detect_kernel<<<(NE + 255) / 256, 256, 0, stream>>>((const unsigned*)eidx, flag);

    if (ws_size >= WS_NEED) {
        unsigned* off = (unsigned*)(ws + WS_OFF);
        unsigned* cur = (unsigned*)(ws + WS_CUR);
        unsigned* cnt = (unsigned*)(ws + WS_CNT);
        unsigned* inc = (unsigned*)(ws + WS_INC);

        hipMemsetAsync(cnt, 0, 4u * NN, stream);
        count_kernel<<<(NE + 255) / 256, 256, 0, stream>>>(eidx, flag, cnt);
        scan_kernel<<<1, 1024, 0, stream>>>(cnt, off, cur);
        scatter_kernel<<<(NE + 255) / 256, 256, 0, stream>>>(eidx, flag, cur, inc);
        sheaf_node<<<NN, 256, 0, stream>>>(x, eidx, ea, RbfT, flag, off, inc, out);
    } else {
        hipMemsetAsync(d_out, 0, (size_t)out_size * sizeof(float), stream);
        sheaf_atomic<<<NE / 16, 512, 0, stream>>>(x, eidx, ea, RbfT, flag, out);
    }
}